// Round 5
// baseline (253.878 us; speedup 1.0000x reference)
//
#include <hip/hip_runtime.h>
#include <math.h>

#define NL  1024     // N_LEVELS
#define KP1 9        // K+1
#define NB  4096     // direct-mapped buckets (f32 NaN-boxed answer table)

// d_ws float layout:
//   [0]=lo0  [1]=inv  [2..3] pad
//   [WS_PAIR .. +2064)  float2 pairs {B[i], tab[i]}, i in [0,1032): 1023 real
//                       boundaries, [1023]=INF, 8 INF overrun pads
//   [WS_TB   .. +4096)  f32 per-bucket: answer if pure, NaN|scan-start if mixed
#define WS_PAIR 4
#define WS_TB   (WS_PAIR + 2*(NL+8))   // float idx 2068; total ws 6164 f = 24.7KB

// order-preserving float<->uint map (total order incl. negatives)
__device__ __forceinline__ unsigned oi(float f) {
    unsigned u = __float_as_uint(f);
    return (u & 0x80000000u) ? ~u : (u | 0x80000000u);
}
__device__ __forceinline__ float unoi(unsigned k) {
    return __uint_as_float((k & 0x80000000u) ? (k & 0x7fffffffu) : ~k);
}

// bucket index — MUST be the identical fp32 op sequence in build and main
// kernels (monotone: fp sub/mul-by-positive/trunc/clamp are all monotone).
__device__ __forceinline__ int bidx(float x, float lo0, float inv) {
    float t = (x - lo0) * inv;
    int j = (int)t;              // trunc toward zero; clamped below anyway
    j = j < 0 ? 0 : j;
    j = j > (NB - 1) ? (NB - 1) : j;
    return j;
}

// ---------------------------------------------------------------------------
// Build kernel (1 block, 1024 threads):
//  1. tab[i]  = reference threshold-chain output for level i (exact replica)
//  2. B[i]    = smallest fp32 x where pair (i,i+1) chooses RIGHT, via bit-level
//               binary search of the exact reference predicate !(|x-l|<|x-r|)
//  3. pairs[i] = {B[i], tab[i]}
//  4. tb[j]: lo = #{i: bidx(B[i]) < j}. If no boundary maps to bucket j,
//     every x in bucket j lies strictly between B[lo-1] and B[lo] (by
//     monotonicity of bidx) -> answer is tab[lo]: store it directly.
//     Else store quiet-NaN with payload lo (scan start), detected via t!=t.
// ---------------------------------------------------------------------------
__global__ __launch_bounds__(1024) void build_kernel(
    const float* __restrict__ h, const float* __restrict__ d,
    const float* __restrict__ T, const float* __restrict__ bp,
    float* __restrict__ ws)
{
    __shared__ float s_g[NL];
    __shared__ float s_B[NL];     // 1023 boundaries + [1023]=INF
    __shared__ float s_tab[NL];   // per-level answers
    __shared__ int   s_jb[NL];    // bidx of each boundary + sentinel
    __shared__ float s_lo0, s_inv;

    const int tid = threadIdx.x;
    float g = h[tid * KP1];
    s_g[tid] = g;

    // 1. out-value table (exact replica of reference fp32 sequence)
    float outv;
    {
        float v = g, o = 0.0f, b = bp[0];
#pragma unroll
        for (int t = 1; t <= 8; ++t) {
            float z = ((v - T[t]) >= 0.0f) ? 1.0f : 0.0f;
            o = o + z * d[t];
            if (t != 8) v = h[tid * KP1 + (t + 1)];
        }
        outv = o - b;
    }
    s_tab[tid] = outv;
    __syncthreads();

    // 2. exact fp32 decision boundary per adjacent pair
    if (tid < NL - 1) {
        float l = s_g[tid], r = s_g[tid + 1];
        unsigned a = oi(l), b2 = oi(r);   // predicate false at l, true at r
        while (a < b2) {
            unsigned m = a + ((b2 - a) >> 1);
            float xm = unoi(m);
            float dl = fabsf(xm - l), dr = fabsf(xm - r);
            if (!(dl < dr)) b2 = m; else a = m + 1;
        }
        s_B[tid] = unoi(a);
    } else {
        s_B[tid] = INFINITY;
    }
    __syncthreads();

    if (tid == 0) {
        float lo0 = s_B[0];
        float inv = (float)NB / (s_B[NL - 2] - lo0);
        s_lo0 = lo0; s_inv = inv;
        ws[0] = lo0; ws[1] = inv;
    }
    __syncthreads();

    float lo0 = s_lo0, inv = s_inv;
    s_jb[tid] = (tid < NL - 1) ? bidx(s_B[tid], lo0, inv) : 0x7fffffff;

    // 3. interleaved {boundary, value} pairs + overrun pads
    ws[WS_PAIR + 2 * tid]     = s_B[tid];
    ws[WS_PAIR + 2 * tid + 1] = outv;
    if (tid < 8) {
        ws[WS_PAIR + 2 * (NL + tid)]     = INFINITY;
        ws[WS_PAIR + 2 * (NL + tid) + 1] = 0.0f;
    }
    __syncthreads();

    // 4. per-bucket NaN-boxed direct table
    for (int j = tid; j < NB; j += 1024) {
        int lo = 0;
#pragma unroll
        for (int s = 512; s >= 1; s >>= 1)
            if (s_jb[lo + s - 1] < j) lo += s;
        // lo in [0,1023]; s_jb[1023] = sentinel (never == j)
        float v;
        if (s_jb[lo] == j)
            v = __uint_as_float(0x7FC00000u | (unsigned)lo);  // mixed: qNaN|lo
        else
            v = s_tab[lo];                                    // pure: answer
        ws[WS_TB + j] = v;
    }
}

// ---------------------------------------------------------------------------
// Main kernel. Round-5: cut LDS gathers/element 3.0 -> 1.5.
// R0-R4 all pinned at 82-86 us across chain-depth/occupancy/branch changes;
// the invariant was ~3 random LDS gathers per element (~50% LDS-pipe busy,
// the hottest resource). New: one f32 gather tb[j] answers ~75% of elements
// outright (pure bucket); NaN payload carries the scan start for the rest,
// which take the exec-masked candidate-pair select (~16/64 lanes active).
// LDS = 16 KB tb + 8.3 KB pairs ~= 24.4 KB -> 6 blocks/CU (24 waves).
// ---------------------------------------------------------------------------
typedef float vf4 __attribute__((ext_vector_type(4)));

__device__ __forceinline__ float resolve(float x, const float2* __restrict__ pp,
                                         float t)
{
    int n = (int)(__float_as_uint(t) & 1023u);
    float2 a = pp[n], b = pp[n + 1];
    float r = (a.x > x) ? a.y : b.y;
    if (__builtin_expect(b.x <= x, 0)) {
        int m = n + 2; float2 p = pp[m];
        while (p.x <= x) { ++m; p = pp[m]; }   // INF pads terminate
        r = p.y;
    }
    return r;
}

__device__ __forceinline__ float4 proc4(float4 v,
                                        const float2* __restrict__ pp,
                                        const float* __restrict__ tb,
                                        float lo0, float inv)
{
    // phase 1: 4 independent b32 gathers issue together
    float t0 = tb[bidx(v.x, lo0, inv)];
    float t1 = tb[bidx(v.y, lo0, inv)];
    float t2 = tb[bidx(v.z, lo0, inv)];
    float t3 = tb[bidx(v.w, lo0, inv)];
    // phase 2: ~25%-of-lanes masked fallbacks (NaN test t!=t)
    if (t0 != t0) t0 = resolve(v.x, pp, t0);
    if (t1 != t1) t1 = resolve(v.y, pp, t1);
    if (t2 != t2) t2 = resolve(v.z, pp, t2);
    if (t3 != t3) t3 = resolve(v.w, pp, t3);
    return make_float4(t0, t1, t2, t3);
}

__global__ __launch_bounds__(256) void ps_act_kernel(
    const float* __restrict__ x,
    const float* __restrict__ ws,
    float* __restrict__ out,
    int n4)
{
    __shared__ __align__(16) float spair[2 * (NL + 8)];
    __shared__ __align__(16) float stb[NB];

    const int tid = threadIdx.x;
    // vectorized staging: 516 float4s of pairs, 1024 float4s of tb
    {
        const float4* wp4 = (const float4*)(ws + WS_PAIR);
        float4* sp4 = (float4*)spair;
        for (int i = tid; i < 2 * (NL + 8) / 4; i += 256) sp4[i] = wp4[i];
        const float4* wt4 = (const float4*)(ws + WS_TB);
        float4* st4 = (float4*)stb;
        for (int i = tid; i < NB / 4; i += 256) st4[i] = wt4[i];
    }
    const float lo0 = ws[0];
    const float inv = ws[1];
    __syncthreads();

    const float4* __restrict__ x4 = (const float4*)x;
    float4* __restrict__ o4 = (float4*)out;
    const float2* pp = (const float2*)spair;
    const int stride = gridDim.x * blockDim.x;

    for (int i4 = blockIdx.x * blockDim.x + tid; i4 < n4; i4 += 2 * stride) {
        const int j4 = i4 + stride;
        // two independent float4 loads issue back-to-back
        float4 c0 = x4[i4];
        float4 c1 = make_float4(0.f, 0.f, 0.f, 0.f);
        if (j4 < n4) c1 = x4[j4];

        float4 r0 = proc4(c0, pp, stb, lo0, inv);
        // out is write-only: nontemporal stores keep x resident in L2/L3
        vf4 o0 = {r0.x, r0.y, r0.z, r0.w};
        __builtin_nontemporal_store(o0, (vf4*)&o4[i4]);

        if (j4 < n4) {
            float4 r1 = proc4(c1, pp, stb, lo0, inv);
            vf4 o1 = {r1.x, r1.y, r1.z, r1.w};
            __builtin_nontemporal_store(o1, (vf4*)&o4[j4]);
        }
    }
}

extern "C" void kernel_launch(void* const* d_in, const int* in_sizes, int n_in,
                              void* d_out, int out_size, void* d_ws, size_t ws_size,
                              hipStream_t stream) {
    const float* x = (const float*)d_in[0];
    const float* h = (const float*)d_in[1];
    const float* d = (const float*)d_in[2];
    const float* T = (const float*)d_in[3];
    const float* b = (const float*)d_in[4];
    float* out = (float*)d_out;
    float* ws  = (float*)d_ws;

    int n  = in_sizes[0];
    int n4 = n / 4;

    build_kernel<<<1, 1024, 0, stream>>>(h, d, T, b, ws);
    // 4096 blocks x 256: each thread sweeps 8 float4s, 2 per iteration.
    ps_act_kernel<<<4096, 256, 0, stream>>>(x, ws, out, n4);
}